// Round 10
// baseline (249.435 us; speedup 1.0000x reference)
//
#include <hip/hip_runtime.h>
#include <math.h>

#define N_NODES_C 100000
#define N_EDGES_C 1600000
#define DIM 64
#define G3 192
#define SCAN_B 1024
#define N_SCAN_BLOCKS ((N_NODES_C + SCAN_B - 1) / SCAN_B)   // 98

typedef short bf16x8 __attribute__((ext_vector_type(8)));
typedef float f32x4 __attribute__((ext_vector_type(4)));

__device__ __forceinline__ unsigned short bf16_rne(float f) {
    unsigned int u = __float_as_uint(f);
    return (unsigned short)((u + 0x7FFFu + ((u >> 16) & 1u)) >> 16);
}

// split f into hi (truncated bf16) and lo (rne bf16 of residual), packed x2
__device__ __forceinline__ void split2(float f0, float f1,
                                       unsigned int& hi, unsigned int& lo) {
    const unsigned int u0 = __float_as_uint(f0);
    const unsigned int u1 = __float_as_uint(f1);
    const float l0 = f0 - __uint_as_float(u0 & 0xFFFF0000u);
    const float l1 = f1 - __uint_as_float(u1 & 0xFFFF0000u);
    hi = (u0 >> 16) | ((u1 >> 16) << 16);
    lo = (unsigned int)bf16_rne(l0) | ((unsigned int)bf16_rne(l1) << 16);
}

__device__ __forceinline__ float bf16f(unsigned short h) {
    return __uint_as_float(((unsigned int)h) << 16);
}

// ---------------------------------------------------------------------------
// Phase 1a: histogram receivers, record per-edge rank within its segment
// ---------------------------------------------------------------------------
__global__ void hist_kernel(const int* __restrict__ receivers,
                            int* __restrict__ count,
                            int* __restrict__ rank) {
    int e = blockIdx.x * blockDim.x + threadIdx.x;
    if (e >= N_EDGES_C) return;
    int r = receivers[e];
    rank[e] = __hip_atomic_fetch_add(&count[r], 1,
                                     __ATOMIC_RELAXED, __HIP_MEMORY_SCOPE_AGENT);
}

// ---------------------------------------------------------------------------
// Phase 1b: scan. offsets[] = block-local exclusive; bsums[] = per-block base
// ---------------------------------------------------------------------------
__global__ void scan1_kernel(const int* __restrict__ count,
                             int* __restrict__ offsets,
                             int* __restrict__ bsums) {
    __shared__ int wsum[16];
    const int gid  = blockIdx.x * SCAN_B + threadIdx.x;
    const int lane = threadIdx.x & 63;
    const int wv   = threadIdx.x >> 6;
    int c = (gid < N_NODES_C) ? count[gid] : 0;
    int x = c;
    #pragma unroll
    for (int o = 1; o < 64; o <<= 1) {
        int v = __shfl_up(x, o);
        if (lane >= o) x += v;
    }
    if (lane == 63) wsum[wv] = x;
    __syncthreads();
    if (wv == 0) {
        int s = (lane < 16) ? wsum[lane] : 0;
        #pragma unroll
        for (int o = 1; o < 16; o <<= 1) {
            int v = __shfl_up(s, o);
            if (lane >= o) s += v;
        }
        if (lane < 16) wsum[lane] = s;   // inclusive over waves
    }
    __syncthreads();
    int woff = (wv == 0) ? 0 : wsum[wv - 1];
    if (gid < N_NODES_C) offsets[gid] = woff + x - c;
    if (threadIdx.x == SCAN_B - 1) bsums[blockIdx.x] = wsum[15];
}

__global__ void scan2_kernel(int* __restrict__ bsums) {
    __shared__ int w0tot;
    const int i    = threadIdx.x;
    const int lane = threadIdx.x & 63;
    const int wv   = threadIdx.x >> 6;
    int c = (i < N_SCAN_BLOCKS) ? bsums[i] : 0;
    int x = c;
    #pragma unroll
    for (int o = 1; o < 64; o <<= 1) {
        int v = __shfl_up(x, o);
        if (lane >= o) x += v;
    }
    if (wv == 0 && lane == 63) w0tot = x;
    __syncthreads();
    int add = (wv == 1) ? w0tot : 0;
    if (i < N_SCAN_BLOCKS) bsums[i] = add + x - c;   // exclusive
}

// ---------------------------------------------------------------------------
// Phase 1c: write permutation (CSR edge lists); bsums applied inline
// ---------------------------------------------------------------------------
__global__ void permw_kernel(const int* __restrict__ receivers,
                             const int* __restrict__ offsets,
                             const int* __restrict__ bsums,
                             const int* __restrict__ rank,
                             int* __restrict__ perm) {
    int e = blockIdx.x * blockDim.x + threadIdx.x;
    if (e >= N_EDGES_C) return;
    int r = receivers[e];
    perm[offsets[r] + bsums[r >> 10] + rank[e]] = e;
}

// ---------------------------------------------------------------------------
// Prep: weights -> swizzled split-bf16 hi/lo images (one-time, L2-resident).
// Image layout per matrix: hi[12288] | lo[12288] ushorts;
// addr(col, ch) = col*64 + ((ch ^ (col&7))<<3), ch = K-octet 0..7.
// 1536 chunks per matrix (FIX: mat = ci/1536, was ci>>11).
// ---------------------------------------------------------------------------
__global__ void prep_w_kernel(const float* __restrict__ w_ih,
                              const float* __restrict__ w_hh,
                              unsigned short* __restrict__ img_w) {
    const int ci  = blockIdx.x * 256 + threadIdx.x;   // 3072 chunks
    if (ci >= 3072) return;
    const int mat = ci / 1536;           // 0: w_ih, 1: w_hh
    const int rem = ci - mat * 1536;
    const int col = rem >> 3;
    const int ch  = rem & 7;
    const float* w = mat ? w_hh : w_ih;
    const float4 f0 = *reinterpret_cast<const float4*>(w + col * 64 + ch * 8);
    const float4 f1 = *reinterpret_cast<const float4*>(w + col * 64 + ch * 8 + 4);
    unsigned int hi[4], lo[4];
    split2(f0.x, f0.y, hi[0], lo[0]);
    split2(f0.z, f0.w, hi[1], lo[1]);
    split2(f1.x, f1.y, hi[2], lo[2]);
    split2(f1.z, f1.w, hi[3], lo[3]);
    unsigned short* dst = img_w + mat * 24576 + col * 64 + ((ch ^ (col & 7)) << 3);
    *reinterpret_cast<uint4*>(dst)         = make_uint4(hi[0], hi[1], hi[2], hi[3]);
    *reinterpret_cast<uint4*>(dst + 12288) = make_uint4(lo[0], lo[1], lo[2], lo[3]);
}

// ---------------------------------------------------------------------------
// Prep: nodes -> swizzled split-bf16 hi/lo images.
// Row layout: 64 bf16 = 8 chunks of 8; addr(row,ch) = row*64 + ((ch^(row&7))<<3)
// ---------------------------------------------------------------------------
__global__ void prep_nodes_kernel(const float* __restrict__ nodes,
                                  unsigned short* __restrict__ n_hi,
                                  unsigned short* __restrict__ n_lo) {
    const int t = blockIdx.x * 256 + threadIdx.x;    // N*16 quarter-rows
    if (t >= N_NODES_C * 16) return;
    const int row = t >> 4;
    const int cc  = t & 15;                          // 4-col group
    const float4 f = *reinterpret_cast<const float4*>(nodes + (size_t)row * 64 + cc * 4);
    unsigned int h0, l0, h1, l1;
    split2(f.x, f.y, h0, l0);
    split2(f.z, f.w, h1, l1);
    const int addr = row * 64 + (((cc >> 1) ^ (row & 7)) << 3) + ((cc & 1) << 2);
    *reinterpret_cast<uint2*>(n_hi + addr) = make_uint2(h0, h1);
    *reinterpret_cast<uint2*>(n_lo + addr) = make_uint2(l0, l1);
}

// ---------------------------------------------------------------------------
// Phase 2: gather-aggregate (round-7 issue structure, at the random-read
// ceiling). Epilogue writes aggr as swizzled split-bf16 hi/lo images.
// ---------------------------------------------------------------------------
__global__ __launch_bounds__(256)
void gather_kernel(const float* __restrict__ edges,
                   const int* __restrict__ perm,
                   const int* __restrict__ offsets,
                   const int* __restrict__ bsums,
                   const int* __restrict__ count,
                   unsigned short* __restrict__ a_hi,
                   unsigned short* __restrict__ a_lo) {
    const int w    = (blockIdx.x << 2) | (threadIdx.x >> 6);
    const int lane = threadIdx.x & 63;
    if (w >= N_NODES_C) return;
    const int g    = lane >> 4;
    const int c4   = (lane & 15) << 2;
    const int start = offsets[w] + bsums[w >> 10];
    const int cnt   = count[w];

    float4 a0 = make_float4(0.f, 0.f, 0.f, 0.f);
    float4 a1 = a0, a2 = a0, a3 = a0;

    int done = 0;
    while (done < cnt) {
        const int pv  = perm[start + min(done + lane, cnt - 1)];
        const int lim = min(cnt - done, 64);
        const int nq  = (lim + 15) >> 4;
        for (int q = 0; q < nq; ++q) {
            const int rbase = q << 4;
            #pragma unroll
            for (int b = 0; b < 4; ++b) {
                const int rr  = rbase + (b << 2) + g;
                const int src = min(rr, lim - 1);
                const int e   = __shfl(pv, src);
                const float4 v = *reinterpret_cast<const float4*>(
                    edges + (size_t)e * DIM + c4);
                const float m = (rr < lim) ? 1.f : 0.f;
                if (b == 0) { a0.x += v.x*m; a0.y += v.y*m; a0.z += v.z*m; a0.w += v.w*m; }
                if (b == 1) { a1.x += v.x*m; a1.y += v.y*m; a1.z += v.z*m; a1.w += v.w*m; }
                if (b == 2) { a2.x += v.x*m; a2.y += v.y*m; a2.z += v.z*m; a2.w += v.w*m; }
                if (b == 3) { a3.x += v.x*m; a3.y += v.y*m; a3.z += v.z*m; a3.w += v.w*m; }
            }
        }
        done += 64;
    }

    float4 s;
    s.x = (a0.x + a1.x) + (a2.x + a3.x);
    s.y = (a0.y + a1.y) + (a2.y + a3.y);
    s.z = (a0.z + a1.z) + (a2.z + a3.z);
    s.w = (a0.w + a1.w) + (a2.w + a3.w);
    #pragma unroll
    for (int m = 16; m <= 32; m <<= 1) {
        s.x += __shfl_xor(s.x, m);
        s.y += __shfl_xor(s.y, m);
        s.z += __shfl_xor(s.z, m);
        s.w += __shfl_xor(s.w, m);
    }
    if (lane < 16) {
        const int l15 = lane;
        unsigned int h0, l0, h1, l1;
        split2(s.x, s.y, h0, l0);
        split2(s.z, s.w, h1, l1);
        const int addr = w * 64 + ((((l15) >> 1) ^ (w & 7)) << 3) + ((l15 & 1) << 2);
        *reinterpret_cast<uint2*>(a_hi + addr) = make_uint2(h0, h1);
        *reinterpret_cast<uint2*>(a_lo + addr) = make_uint2(l0, l1);
    }
}

// ---------------------------------------------------------------------------
// Phase 3: GRU via MFMA from precomputed images. Block = 256 thr / 64 nodes;
// wave tile = 16 rows x 192 cols; 3-product split-bf16.
// Staging is a pure uint4 copy (no conversion VALU in the hot kernel).
// LDS: weights 48KB + A hi/lo 16KB = 64KB, 2 blocks/CU.
// ---------------------------------------------------------------------------
__global__ __launch_bounds__(256, 2)
void gru_mfma_kernel(const unsigned short* __restrict__ img_w,  // 4*12288
                     const unsigned short* __restrict__ aggr_hi,
                     const unsigned short* __restrict__ aggr_lo,
                     const unsigned short* __restrict__ nodes_hi,
                     const unsigned short* __restrict__ nodes_lo,
                     const float* __restrict__ b_ih,
                     const float* __restrict__ b_hh,
                     float* __restrict__ out) {
    __shared__ __align__(16) unsigned short s_w[24576];  // hi | lo, 48 KB
    __shared__ __align__(16) unsigned short s_a[8192];   // hi | lo, 16 KB

    const int tid  = threadIdx.x;
    const int lane = tid & 63;
    const int wave = tid >> 6;
    const int nb   = blockIdx.x * 64;
    const int l15  = lane & 15;
    const int lg   = lane >> 4;
    const int arow = (wave << 4) + l15;

    float bir[4], biz[4], bin_[4], bhr[4], bhz[4], bhn[4];
    #pragma unroll
    for (int t = 0; t < 4; ++t) {
        const int o = l15 + (t << 4);
        bir[t] = b_ih[o]; biz[t] = b_ih[64 + o]; bin_[t] = b_ih[128 + o];
        bhr[t] = b_hh[o]; bhz[t] = b_hh[64 + o]; bhn[t] = b_hh[128 + o];
    }

    f32x4 accA[12], accB[12];
    #pragma unroll
    for (int ct = 0; ct < 12; ++ct) { accA[ct] = (f32x4)(0.f); accB[ct] = (f32x4)(0.f); }

    // ================= GEMM 1: gi = aggr @ w_ih.T =================
    {
        const uint4* wsrc = reinterpret_cast<const uint4*>(img_w);
        uint4* wdst = reinterpret_cast<uint4*>(s_w);
        #pragma unroll
        for (int i = 0; i < 12; ++i) wdst[tid + i * 256] = wsrc[tid + i * 256];
        const uint4* hsrc = reinterpret_cast<const uint4*>(aggr_hi + (size_t)nb * 64);
        const uint4* lsrc = reinterpret_cast<const uint4*>(aggr_lo + (size_t)nb * 64);
        uint4* adst = reinterpret_cast<uint4*>(s_a);
        #pragma unroll
        for (int i = 0; i < 2; ++i) {
            adst[tid + i * 256]       = hsrc[tid + i * 256];
            adst[512 + tid + i * 256] = lsrc[tid + i * 256];
        }
    }
    __syncthreads();

    #pragma unroll
    for (int kt = 0; kt < 2; ++kt) {
        const int ach = ((kt * 4 + lg) ^ (arow & 7)) << 3;
        const bf16x8 ahi = *reinterpret_cast<const bf16x8*>(&s_a[arow * 64 + ach]);
        const bf16x8 alo = *reinterpret_cast<const bf16x8*>(&s_a[4096 + arow * 64 + ach]);
        #pragma unroll
        for (int ct = 0; ct < 12; ++ct) {
            const int col = ct * 16 + l15;
            const int sw  = ((kt * 4 + lg) ^ (col & 7)) << 3;
            const bf16x8 bhi = *reinterpret_cast<const bf16x8*>(&s_w[col * 64 + sw]);
            const bf16x8 blo = *reinterpret_cast<const bf16x8*>(&s_w[12288 + col * 64 + sw]);
            accA[ct] = __builtin_amdgcn_mfma_f32_16x16x32_bf16(ahi, bhi, accA[ct], 0, 0, 0);
            accA[ct] = __builtin_amdgcn_mfma_f32_16x16x32_bf16(alo, bhi, accA[ct], 0, 0, 0);
            accA[ct] = __builtin_amdgcn_mfma_f32_16x16x32_bf16(ahi, blo, accA[ct], 0, 0, 0);
        }
    }
    __syncthreads();

    // ================= GEMM 2: gh = nodes @ w_hh.T =================
    {
        const uint4* wsrc = reinterpret_cast<const uint4*>(img_w + 24576);
        uint4* wdst = reinterpret_cast<uint4*>(s_w);
        #pragma unroll
        for (int i = 0; i < 12; ++i) wdst[tid + i * 256] = wsrc[tid + i * 256];
        const uint4* hsrc = reinterpret_cast<const uint4*>(nodes_hi + (size_t)nb * 64);
        const uint4* lsrc = reinterpret_cast<const uint4*>(nodes_lo + (size_t)nb * 64);
        uint4* adst = reinterpret_cast<uint4*>(s_a);
        #pragma unroll
        for (int i = 0; i < 2; ++i) {
            adst[tid + i * 256]       = hsrc[tid + i * 256];
            adst[512 + tid + i * 256] = lsrc[tid + i * 256];
        }
    }
    __syncthreads();

    #pragma unroll
    for (int kt = 0; kt < 2; ++kt) {
        const int ach = ((kt * 4 + lg) ^ (arow & 7)) << 3;
        const bf16x8 ahi = *reinterpret_cast<const bf16x8*>(&s_a[arow * 64 + ach]);
        const bf16x8 alo = *reinterpret_cast<const bf16x8*>(&s_a[4096 + arow * 64 + ach]);
        #pragma unroll
        for (int ct = 0; ct < 12; ++ct) {
            const int col = ct * 16 + l15;
            const int sw  = ((kt * 4 + lg) ^ (col & 7)) << 3;
            const bf16x8 bhi = *reinterpret_cast<const bf16x8*>(&s_w[col * 64 + sw]);
            const bf16x8 blo = *reinterpret_cast<const bf16x8*>(&s_w[12288 + col * 64 + sw]);
            accB[ct] = __builtin_amdgcn_mfma_f32_16x16x32_bf16(ahi, bhi, accB[ct], 0, 0, 0);
            accB[ct] = __builtin_amdgcn_mfma_f32_16x16x32_bf16(alo, bhi, accB[ct], 0, 0, 0);
            accB[ct] = __builtin_amdgcn_mfma_f32_16x16x32_bf16(ahi, blo, accB[ct], 0, 0, 0);
        }
    }

    // ====== gates + store (s_a holds nodes hi/lo; h = hi + lo) ======
    #pragma unroll
    for (int t = 0; t < 4; ++t) {
        #pragma unroll
        for (int rg = 0; rg < 4; ++rg) {
            const int rr   = (wave << 4) + (lg << 2) + rg;
            const int node = nb + rr;
            const int o    = l15 + (t << 4);
            const float ir = accA[t][rg]     + bir[t];
            const float iz = accA[4 + t][rg] + biz[t];
            const float inn= accA[8 + t][rg] + bin_[t];
            const float hr = accB[t][rg]     + bhr[t];
            const float hz = accB[4 + t][rg] + bhz[t];
            const float hn = accB[8 + t][rg] + bhn[t];
            const float r = 1.f / (1.f + __expf(-(ir + hr)));
            const float z = 1.f / (1.f + __expf(-(iz + hz)));
            float tt = inn + r * hn;
            tt = fminf(fmaxf(tt, -15.f), 15.f);
            const float e2 = __expf(2.f * tt);
            const float ng = (e2 - 1.f) / (e2 + 1.f);
            const int idx = rr * 64 + (((o >> 3) ^ (rr & 7)) << 3) + (o & 7);
            const float h = bf16f(s_a[idx]) + bf16f(s_a[4096 + idx]);
            if (node < N_NODES_C)
                out[(size_t)node * 64 + o] = (1.f - z) * ng + z * h;
        }
    }
}

// ---------------------------------------------------------------------------
extern "C" void kernel_launch(void* const* d_in, const int* in_sizes, int n_in,
                              void* d_out, int out_size, void* d_ws, size_t ws_size,
                              hipStream_t stream) {
    const float* edges     = (const float*)d_in[0];
    const float* nodes     = (const float*)d_in[1];
    const int*   receivers = (const int*)d_in[2];
    const float* w_ih      = (const float*)d_in[3];
    const float* w_hh      = (const float*)d_in[4];
    const float* b_ih      = (const float*)d_in[5];
    const float* b_hh      = (const float*)d_in[6];
    float* out = (float*)d_out;

    // workspace layout
    int* ws      = (int*)d_ws;
    int* count   = ws;                       // 100000
    int* offsets = ws + N_NODES_C;           // 100000
    int* rank    = ws + 2 * N_NODES_C;       // 1.6M
    int* perm    = rank + N_EDGES_C;         // 1.6M
    int* bsums   = perm + N_EDGES_C;         // 128
    // images (ushort), 16B-aligned: starts at int offset 3,400,192
    unsigned short* img_w   = (unsigned short*)(ws + 3400192);  // 4*12288
    unsigned short* aggr_hi = img_w + 4 * 12288;                // 6.4M each
    unsigned short* aggr_lo = aggr_hi + (size_t)N_NODES_C * 64;
    unsigned short* n_hi    = aggr_lo + (size_t)N_NODES_C * 64;
    unsigned short* n_lo    = n_hi    + (size_t)N_NODES_C * 64;

    hipMemsetAsync(count, 0, N_NODES_C * sizeof(int), stream);

    prep_w_kernel<<<12, 256, 0, stream>>>(w_ih, w_hh, img_w);
    prep_nodes_kernel<<<(N_NODES_C * 16 + 255) / 256, 256, 0, stream>>>(nodes, n_hi, n_lo);

    hist_kernel<<<(N_EDGES_C + 255) / 256, 256, 0, stream>>>(receivers, count, rank);
    scan1_kernel<<<N_SCAN_BLOCKS, SCAN_B, 0, stream>>>(count, offsets, bsums);
    scan2_kernel<<<1, 128, 0, stream>>>(bsums);
    permw_kernel<<<(N_EDGES_C + 255) / 256, 256, 0, stream>>>(receivers, offsets, bsums, rank, perm);

    gather_kernel<<<(N_NODES_C + 3) / 4, 256, 0, stream>>>(
        edges, perm, offsets, bsums, count, aggr_hi, aggr_lo);

    gru_mfma_kernel<<<(N_NODES_C + 63) / 64, 256, 0, stream>>>(
        img_w, aggr_hi, aggr_lo, n_hi, n_lo, b_ih, b_hh, out);
}